// Round 1
// baseline (96.595 us; speedup 1.0000x reference)
//
#include <hip/hip_runtime.h>

namespace {

constexpr int Dd = 8, Hh = 512, Ww = 512, Bb = 2;
constexpr int PLANE = Hh * Ww;                         // 262144
constexpr size_t COORDS_SZ = (size_t)Bb * 3 * Dd * PLANE;  // 12582912

// One thread computes 4 consecutive W-voxels. float4 loads/stores.
__global__ __launch_bounds__(256) void cqi_kernel(const float* __restrict__ x,
                                                  float* __restrict__ out) {
    const int tx = threadIdx.x;                 // 0..127
    const int ty = threadIdx.y;                 // 0..1
    const int w0 = tx << 2;                     // 0,4,...,508
    const int h  = (blockIdx.y << 1) + ty;      // 0..511
    const int bd = blockIdx.z;                  // b*8 + d
    const int b  = bd >> 3;
    const int d  = bd & 7;

    // depth planes with replicate clamp (stay within same batch: d in [0,7])
    const float* pls[3];
    pls[0] = x + (size_t)(d > 0      ? bd - 1 : bd) * PLANE;
    pls[1] = x + (size_t)bd * PLANE;
    pls[2] = x + (size_t)(d < Dd - 1 ? bd + 1 : bd) * PLANE;

    // rows with replicate clamp
    const int rws[3] = { (h > 0      ? h - 1 : 0)      * Ww,
                          h * Ww,
                         (h < Hh - 1 ? h + 1 : h)      * Ww };

    const int wm = (w0 > 0)        ? w0 - 1 : 0;       // left halo (replicate)
    const int wp = (w0 + 4 < Ww)   ? w0 + 4 : Ww - 1;  // right halo (replicate)

    // r[dplane][hrow][0..5] = window [w0-1, w0, w0+1, w0+2, w0+3, w0+4] (clamped)
    float r[3][3][6];
#pragma unroll
    for (int a = 0; a < 3; ++a) {
#pragma unroll
        for (int e = 0; e < 3; ++e) {
            const float* p = pls[a] + rws[e];
            const float4 q = *reinterpret_cast<const float4*>(p + w0);
            r[a][e][0] = p[wm];
            r[a][e][1] = q.x; r[a][e][2] = q.y; r[a][e][3] = q.z; r[a][e][4] = q.w;
            r[a][e][5] = p[wp];
        }
    }

    float oc0[4], oc1[4], oc2[4], oy[4];
#pragma unroll
    for (int i = 0; i < 4; ++i) {
        // v[D][H][W] neighborhood, 0=minus,1=center,2=plus
        float v[3][3][3];
#pragma unroll
        for (int a = 0; a < 3; ++a)
#pragma unroll
            for (int e = 0; e < 3; ++e)
#pragma unroll
                for (int cc = 0; cc < 3; ++cc)
                    v[a][e][cc] = r[a][e][i + cc];

        const float c0 = v[1][1][1];

        // first-order central diffs (b = [dx, dy, ds])
        const float fx = 0.5f * (v[1][1][2] - v[1][1][0]);
        const float fy = 0.5f * (v[1][2][1] - v[1][0][1]);
        const float fs = 0.5f * (v[2][1][1] - v[0][1][1]);

        // second-order (cross terms x0.25 per reference)
        const float dxx = v[1][1][0] + v[1][1][2] - 2.0f * c0;
        const float dyy = v[1][0][1] + v[1][2][1] - 2.0f * c0;
        const float dss = v[0][1][1] + v[2][1][1] - 2.0f * c0;
        const float dxy = 0.25f * (v[1][0][0] + v[1][2][2] - v[1][2][0] - v[1][0][2]);
        const float dys = 0.25f * (v[0][0][1] + v[2][2][1] - v[2][0][1] - v[0][2][1]);
        const float dxs = 0.25f * (v[0][1][0] + v[2][1][2] - v[2][1][0] - v[0][1][2]);

        // NMS: max over clamped 27 == maxpool3d with -inf padding (clamped
        // duplicates are in-bounds window values; center always included)
        float mx = v[0][0][0];
#pragma unroll
        for (int a = 0; a < 3; ++a)
#pragma unroll
            for (int e = 0; e < 3; ++e)
#pragma unroll
                for (int cc = 0; cc < 3; ++cc)
                    mx = fmaxf(mx, v[a][e][cc]);
        const bool nms = (c0 == mx);

        // det per JAX's explicit 3x3 formula; solved = det != 0
        const float det = dxx * dyy * dss + dxy * dys * dxs + dxs * dxy * dys
                        - dxs * dyy * dxs - dxx * dys * dys - dxy * dxy * dss;
        const bool solved = (det != 0.0f);

        // adjugate (symmetric) solve: sol = adj(H) * b / det
        const float A00 = dyy * dss - dys * dys;
        const float A01 = dys * dxs - dxy * dss;
        const float A02 = dxy * dys - dyy * dxs;
        const float A11 = dxx * dss - dxs * dxs;
        const float A12 = dxy * dxs - dxx * dys;
        const float A22 = dxx * dyy - dxy * dxy;
        const float inv = 1.0f / det;   // inf if det==0; masked by newnms select
        const float sx = (A00 * fx + A01 * fy + A02 * fs) * inv;
        const float sy = (A01 * fx + A11 * fy + A12 * fs) * inv;
        const float ss = (A02 * fx + A12 * fy + A22 * fs) * inv;

        const bool newnms = nms && solved;
        float dxv = newnms ? -sx : 0.0f;
        float dyv = newnms ? -sy : 0.0f;
        float dsv = newnms ? -ss : 0.0f;

        // zero refinement if any |component| > 0.7 (keep<=0.7 also kills NaN)
        const float mabs = fmaxf(fabsf(dxv), fmaxf(fabsf(dyv), fabsf(dsv)));
        const bool keep = (mabs <= 0.7f);
        dxv = keep ? dxv : 0.0f;
        dyv = keep ? dyv : 0.0f;
        dsv = keep ? dsv : 0.0f;

        const float dyval = 0.5f * (fx * dxv + fy * dyv + fs * dsv);

        oy[i]  = c0 + dyval + (newnms ? 10.0f : 0.0f);
        // kornia quirk: coords ch0 = d + ds, ch1 = w + dy, ch2 = h + dx
        oc0[i] = (float)d + dsv;
        oc1[i] = (float)(w0 + i) + dyv;
        oc2[i] = (float)h + dxv;
    }

    float* coords = out;
    float* ymax   = out + COORDS_SZ;
    const size_t idx = (size_t)(h * Ww) + w0;
    const size_t cb  = ((size_t)(b * 3) * Dd + d) * PLANE + idx;
    *reinterpret_cast<float4*>(coords + cb)                          = make_float4(oc0[0], oc0[1], oc0[2], oc0[3]);
    *reinterpret_cast<float4*>(coords + cb + (size_t)Dd * PLANE)     = make_float4(oc1[0], oc1[1], oc1[2], oc1[3]);
    *reinterpret_cast<float4*>(coords + cb + (size_t)2 * Dd * PLANE) = make_float4(oc2[0], oc2[1], oc2[2], oc2[3]);
    *reinterpret_cast<float4*>(ymax + (size_t)bd * PLANE + idx)      = make_float4(oy[0], oy[1], oy[2], oy[3]);
}

} // namespace

extern "C" void kernel_launch(void* const* d_in, const int* in_sizes, int n_in,
                              void* d_out, int out_size, void* d_ws, size_t ws_size,
                              hipStream_t stream) {
    const float* x = (const float*)d_in[0];
    float* out = (float*)d_out;
    dim3 grid(1, Hh / 2, Bb * Dd);   // (1, 256, 16)
    dim3 block(Ww / 4, 2, 1);        // (128, 2) = 256 threads
    hipLaunchKernelGGL(cqi_kernel, grid, block, 0, stream, x, out);
}

// Round 2
// 92.204 us; speedup vs baseline: 1.0476x; 1.0476x over previous
//
#include <hip/hip_runtime.h>

namespace {

constexpr int Dd = 8, Hh = 512, Ww = 512, Bb = 2;
constexpr int PLANE = Hh * Ww;                              // 262144
constexpr size_t COORDS_SZ = (size_t)Bb * 3 * Dd * PLANE;   // 12582912

// One wave (64 lanes) processes one full image row (512 px): lane l holds
// w = 8l..8l+7 via two float4 loads per (plane,row). W-halos come from
// cross-lane shuffles; lane-0/63 clamps coincide with the replicate border.
// 18 float4 loads per 8 voxels (vs 27 loads per 4 voxels before).
__global__ __launch_bounds__(256) void cqi_kernel(const float* __restrict__ x,
                                                  float* __restrict__ out) {
    const int lane = threadIdx.x & 63;
    const int gid  = (blockIdx.x << 2) | (threadIdx.x >> 6);  // row id 0..8191
    const int h  = gid & (Hh - 1);
    const int bd = gid >> 9;                                  // b*8 + d, 0..15
    const int b  = bd >> 3;
    const int d  = bd & 7;

    // depth planes with replicate clamp (within batch)
    const float* pl[3];
    pl[0] = x + (size_t)(d > 0      ? bd - 1 : bd) * PLANE;
    pl[1] = x + (size_t)bd * PLANE;
    pl[2] = x + (size_t)(d < Dd - 1 ? bd + 1 : bd) * PLANE;
    // rows with replicate clamp
    const int rw[3] = { (h > 0      ? h - 1 : 0) * Ww,
                         h * Ww,
                        (h < Hh - 1 ? h + 1 : h) * Ww };

    const int w0 = lane << 3;

    // W[a][e][k]: window over w = w0-1 .. w0+8 (k = 0..9), replicate-clamped
    float W[3][3][10];
#pragma unroll
    for (int a = 0; a < 3; ++a) {
#pragma unroll
        for (int e = 0; e < 3; ++e) {
            const float* p = pl[a] + rw[e] + w0;
            const float4 q0 = *reinterpret_cast<const float4*>(p);
            const float4 q1 = *reinterpret_cast<const float4*>(p + 4);
            const float lh = __shfl_up(q1.w, 1);    // lane l-1's w0+7 == our w0-1
            const float rh = __shfl_down(q0.x, 1);  // lane l+1's w0   == our w0+8
            W[a][e][0] = (lane == 0)  ? q0.x : lh;  // replicate at w=0
            W[a][e][1] = q0.x; W[a][e][2] = q0.y; W[a][e][3] = q0.z; W[a][e][4] = q0.w;
            W[a][e][5] = q1.x; W[a][e][6] = q1.y; W[a][e][7] = q1.z; W[a][e][8] = q1.w;
            W[a][e][9] = (lane == 63) ? q1.w : rh;  // replicate at w=511
        }
    }

    float* coords = out;
    float* ymax   = out + COORDS_SZ;
    const size_t idx = (size_t)(h * Ww) + w0;
    const size_t cb  = ((size_t)(b * 3) * Dd + d) * PLANE + idx;
    const size_t yb  = (size_t)bd * PLANE + idx;

    // two halves of 4 voxels each -> float4 stores, bounded live registers
#pragma unroll
    for (int half = 0; half < 2; ++half) {
        float4 oc0, oc1, oc2, oy;
        float* oc0p = &oc0.x; float* oc1p = &oc1.x;
        float* oc2p = &oc2.x; float* oyp = &oy.x;
#pragma unroll
        for (int j = 0; j < 4; ++j) {
            const int i = half * 4 + j;   // window base: columns i, i+1, i+2
            const float c0 = W[1][1][i + 1];

            // first-order central diffs
            const float fx = 0.5f * (W[1][1][i + 2] - W[1][1][i]);
            const float fy = 0.5f * (W[1][2][i + 1] - W[1][0][i + 1]);
            const float fs = 0.5f * (W[2][1][i + 1] - W[0][1][i + 1]);

            // second-order
            const float dxx = W[1][1][i] + W[1][1][i + 2] - 2.0f * c0;
            const float dyy = W[1][0][i + 1] + W[1][2][i + 1] - 2.0f * c0;
            const float dss = W[0][1][i + 1] + W[2][1][i + 1] - 2.0f * c0;
            const float dxy = 0.25f * (W[1][0][i] + W[1][2][i + 2] - W[1][2][i] - W[1][0][i + 2]);
            const float dys = 0.25f * (W[0][0][i + 1] + W[2][2][i + 1] - W[2][0][i + 1] - W[0][2][i + 1]);
            const float dxs = 0.25f * (W[0][1][i] + W[2][1][i + 2] - W[2][1][i] - W[0][1][i + 2]);

            // NMS over the (clamped) 27-neighborhood == maxpool3d w/ -inf pad
            float mx = W[0][0][i];
#pragma unroll
            for (int a = 0; a < 3; ++a)
#pragma unroll
                for (int e = 0; e < 3; ++e)
#pragma unroll
                    for (int cc = 0; cc < 3; ++cc)
                        mx = fmaxf(mx, W[a][e][i + cc]);
            const bool nms = (c0 == mx);

            const float det = dxx * dyy * dss + dxy * dys * dxs + dxs * dxy * dys
                            - dxs * dyy * dxs - dxx * dys * dys - dxy * dxy * dss;
            const bool solved = (det != 0.0f);

            // adjugate (symmetric) solve
            const float A00 = dyy * dss - dys * dys;
            const float A01 = dys * dxs - dxy * dss;
            const float A02 = dxy * dys - dyy * dxs;
            const float A11 = dxx * dss - dxs * dxs;
            const float A12 = dxy * dxs - dxx * dys;
            const float A22 = dxx * dyy - dxy * dxy;
            const float inv = 1.0f / det;
            const float sx = (A00 * fx + A01 * fy + A02 * fs) * inv;
            const float sy = (A01 * fx + A11 * fy + A12 * fs) * inv;
            const float ss = (A02 * fx + A12 * fy + A22 * fs) * inv;

            const bool newnms = nms && solved;
            float dxv = newnms ? -sx : 0.0f;
            float dyv = newnms ? -sy : 0.0f;
            float dsv = newnms ? -ss : 0.0f;

            const float mabs = fmaxf(fabsf(dxv), fmaxf(fabsf(dyv), fabsf(dsv)));
            const bool keep = (mabs <= 0.7f);   // also kills NaN
            dxv = keep ? dxv : 0.0f;
            dyv = keep ? dyv : 0.0f;
            dsv = keep ? dsv : 0.0f;

            const float dyval = 0.5f * (fx * dxv + fy * dyv + fs * dsv);

            oyp[j]  = c0 + dyval + (newnms ? 10.0f : 0.0f);
            // kornia channel quirk: ch0 = d + ds, ch1 = w + dy, ch2 = h + dx
            oc0p[j] = (float)d + dsv;
            oc1p[j] = (float)(w0 + i) + dyv;
            oc2p[j] = (float)h + dxv;
        }
        const size_t off = (size_t)(half * 4);
        *reinterpret_cast<float4*>(coords + cb + off)                          = oc0;
        *reinterpret_cast<float4*>(coords + cb + (size_t)Dd * PLANE + off)     = oc1;
        *reinterpret_cast<float4*>(coords + cb + (size_t)2 * Dd * PLANE + off) = oc2;
        *reinterpret_cast<float4*>(ymax + yb + off)                            = oy;
    }
}

} // namespace

extern "C" void kernel_launch(void* const* d_in, const int* in_sizes, int n_in,
                              void* d_out, int out_size, void* d_ws, size_t ws_size,
                              hipStream_t stream) {
    const float* x = (const float*)d_in[0];
    float* out = (float*)d_out;
    // 8192 rows total (B*D*H = 2*8*512); 4 waves (rows) per 256-thread block
    dim3 grid(Bb * Dd * Hh / 4, 1, 1);   // 2048 blocks
    dim3 block(256, 1, 1);
    hipLaunchKernelGGL(cqi_kernel, grid, block, 0, stream, x, out);
}

// Round 3
// 87.234 us; speedup vs baseline: 1.1073x; 1.0570x over previous
//
#include <hip/hip_runtime.h>

namespace {

constexpr int Dd = 8, Hh = 512, Ww = 512, Bb = 2;
constexpr int PLANE = Hh * Ww;                              // 262144
constexpr size_t COORDS_SZ = (size_t)Bb * 3 * Dd * PLANE;   // 12582912

// One wave per image row; lane l holds w = 8l..8l+7 (two float4 loads per
// (plane,row)); W-halos via cross-lane shuffle. Column-wise precompute
// (running max + difference/sum columns) cuts per-voxel VALU ~1.5x.
__global__ __launch_bounds__(256) void cqi_kernel(const float* __restrict__ x,
                                                  float* __restrict__ out) {
    const int lane = threadIdx.x & 63;
    const int gid  = (blockIdx.x << 2) | (threadIdx.x >> 6);  // row id 0..8191
    const int h  = gid & (Hh - 1);
    const int bd = gid >> 9;                                  // b*8 + d
    const int b  = bd >> 3;
    const int d  = bd & 7;

    const float* pl[3];
    pl[0] = x + (size_t)(d > 0      ? bd - 1 : bd) * PLANE;
    pl[1] = x + (size_t)bd * PLANE;
    pl[2] = x + (size_t)(d < Dd - 1 ? bd + 1 : bd) * PLANE;
    const int rw[3] = { (h > 0      ? h - 1 : 0) * Ww,
                         h * Ww,
                        (h < Hh - 1 ? h + 1 : h) * Ww };

    const int w0 = lane << 3;

    // Column accumulators over window k=0..9 (w = w0-1 .. w0+8, clamped):
    float cr[10];   // center row/plane values            W[1][1][k]
    float cm[10];   // max over all 9 (plane,row) pairs
    float fyc[10];  // W[1][2][k] - W[1][0][k]   (dy diff, also dxy column)
    float fsc[10];  // W[2][1][k] - W[0][1][k]   (ds diff, also dxs column)
    float syy[10];  // W[1][0][k] + W[1][2][k]
    float sss[10];  // W[0][1][k] + W[2][1][k]
    float uys[10];  // W[0][0][k] - W[0][2][k] - W[2][0][k] + W[2][2][k]

#pragma unroll
    for (int a = 0; a < 3; ++a) {
#pragma unroll
        for (int e = 0; e < 3; ++e) {
            const float* p = pl[a] + rw[e] + w0;
            const float4 q0 = *reinterpret_cast<const float4*>(p);
            const float4 q1 = *reinterpret_cast<const float4*>(p + 4);
            const float lh = __shfl_up(q1.w, 1);
            const float rh = __shfl_down(q0.x, 1);
            float w[10];
            w[0] = (lane == 0)  ? q0.x : lh;   // replicate at image w=0
            w[1] = q0.x; w[2] = q0.y; w[3] = q0.z; w[4] = q0.w;
            w[5] = q1.x; w[6] = q1.y; w[7] = q1.z; w[8] = q1.w;
            w[9] = (lane == 63) ? q1.w : rh;   // replicate at image w=511
#pragma unroll
            for (int k = 0; k < 10; ++k) {
                if (a == 0 && e == 0) cm[k] = w[k];
                else                  cm[k] = fmaxf(cm[k], w[k]);
                if (a == 1 && e == 1) cr[k] = w[k];
                if (a == 1 && e == 0) { fyc[k] = w[k]; syy[k] = w[k]; }
                if (a == 1 && e == 2) { syy[k] += w[k]; fyc[k] = w[k] - fyc[k]; }
                if (a == 0 && e == 1) { fsc[k] = w[k]; sss[k] = w[k]; }
                if (a == 2 && e == 1) { sss[k] += w[k]; fsc[k] = w[k] - fsc[k]; }
                if (a == 0 && e == 0) uys[k] = w[k];
                if (a == 0 && e == 2) uys[k] -= w[k];
                if (a == 2 && e == 0) uys[k] -= w[k];
                if (a == 2 && e == 2) uys[k] += w[k];
            }
        }
    }

    float* coords = out;
    float* ymax   = out + COORDS_SZ;
    const size_t idx = (size_t)(h * Ww) + w0;
    const size_t cb  = ((size_t)(b * 3) * Dd + d) * PLANE + idx;
    const size_t yb  = (size_t)bd * PLANE + idx;
    const float df = (float)d, hf = (float)h, wf = (float)w0;

#pragma unroll
    for (int half = 0; half < 2; ++half) {
        float4 oc0, oc1, oc2, oy;
        float* oc0p = &oc0.x; float* oc1p = &oc1.x;
        float* oc2p = &oc2.x; float* oyp = &oy.x;
#pragma unroll
        for (int j = 0; j < 4; ++j) {
            const int i = half * 4 + j;
            const float c0 = cr[i + 1];

            const float fx = 0.5f * (cr[i + 2] - cr[i]);
            const float fy = 0.5f * fyc[i + 1];
            const float fs = 0.5f * fsc[i + 1];

            const float dxx = (cr[i] + cr[i + 2]) - 2.0f * c0;
            const float dyy = syy[i + 1] - 2.0f * c0;
            const float dss = sss[i + 1] - 2.0f * c0;
            const float dxy = 0.25f * (fyc[i + 2] - fyc[i]);
            const float dxs = 0.25f * (fsc[i + 2] - fsc[i]);
            const float dys = 0.25f * uys[i + 1];

            const float mx = fmaxf(fmaxf(cm[i], cm[i + 1]), cm[i + 2]);
            const bool nms = (c0 == mx);

            // adjugate first column doubles as det row
            const float A00 = dyy * dss - dys * dys;
            const float A01 = dys * dxs - dxy * dss;
            const float A02 = dxy * dys - dyy * dxs;
            const float det = dxx * A00 + dxy * A01 + dxs * A02;
            const bool solved = (det != 0.0f);

            const float A11 = dxx * dss - dxs * dxs;
            const float A12 = dxy * dxs - dxx * dys;
            const float A22 = dxx * dyy - dxy * dxy;
            const float ninv = -__builtin_amdgcn_rcpf(det);  // -(1/det), approx
            const float sx = (A00 * fx + A01 * fy + A02 * fs) * ninv;  // = -sol_x
            const float sy = (A01 * fx + A11 * fy + A12 * fs) * ninv;
            const float ss = (A02 * fx + A12 * fy + A22 * fs) * ninv;

            const bool newnms = nms && solved;
            float dxv = newnms ? sx : 0.0f;
            float dyv = newnms ? sy : 0.0f;
            float dsv = newnms ? ss : 0.0f;

            const float mabs = fmaxf(fabsf(dxv), fmaxf(fabsf(dyv), fabsf(dsv)));
            const bool keep = (mabs <= 0.7f);   // false for NaN too
            dxv = keep ? dxv : 0.0f;
            dyv = keep ? dyv : 0.0f;
            dsv = keep ? dsv : 0.0f;

            const float dyval = 0.5f * (fx * dxv + fy * dyv + fs * dsv);

            oyp[j]  = c0 + dyval + (newnms ? 10.0f : 0.0f);
            oc0p[j] = df + dsv;
            oc1p[j] = (wf + (float)i) + dyv;
            oc2p[j] = hf + dxv;
        }
        const size_t off = (size_t)(half * 4);
        *reinterpret_cast<float4*>(coords + cb + off)                          = oc0;
        *reinterpret_cast<float4*>(coords + cb + (size_t)Dd * PLANE + off)     = oc1;
        *reinterpret_cast<float4*>(coords + cb + (size_t)2 * Dd * PLANE + off) = oc2;
        *reinterpret_cast<float4*>(ymax + yb + off)                            = oy;
    }
}

} // namespace

extern "C" void kernel_launch(void* const* d_in, const int* in_sizes, int n_in,
                              void* d_out, int out_size, void* d_ws, size_t ws_size,
                              hipStream_t stream) {
    const float* x = (const float*)d_in[0];
    float* out = (float*)d_out;
    dim3 grid(Bb * Dd * Hh / 4, 1, 1);   // 2048 blocks, 1 wave per row
    dim3 block(256, 1, 1);
    hipLaunchKernelGGL(cqi_kernel, grid, block, 0, stream, x, out);
}